// Round 4
// baseline (98.996 us; speedup 1.0000x reference)
//
#include <hip/hip_runtime.h>

// RetinaNet target encoder for MI355X — round 4: register-resident priors,
// scalar-pipe GT loads, amortized per-GT reduce.
// Inputs: bboxes [N,4] f32 xyxy, labels [N] i32, priors [M,4] f32 cxcywh.
// Outputs (concat): reg_targets [M,4] f32, cls_targets [M] (written as f32).
//
// N = 1024, M = 49104. Each IoU pair computed exactly once and feeds:
//  (a) per-prior argmax over GTs — per-thread register track (4 priors/thread)
//  (b) per-GT argmax over priors — wave max + 4 ballots -> global atomicMax
// Packed u64 = (iou_bits<<32) | (0xFFFFFFFF - index): max() == (max iou,
// then smallest index) == numpy first-max argmax. Associative & commutative.
//
// Lane l of wave w in block bx owns priors m = bx*1024 + w*256 + k*64 + l
// (k=0..3): (k, lane) order == m order, so "smallest k, then lowest lane"
// == smallest m (numpy tie-break).

static constexpr float NEG_THRESH = 0.4f;
static constexpr float POS_THRESH = 0.5f;
static constexpr int N_GT = 1024;
static constexpr int MPAD = 49152;           // M rounded up to 1024
static constexpr int PRIORS_PER_BLOCK = 1024;

__device__ __forceinline__ float iou_ab(float ax1, float ay1, float ax2, float ay2,
                                        float area_a,
                                        float bx1, float by1, float bx2, float by2,
                                        float area_b) {
#pragma clang fp contract(off)
    float ltx = fmaxf(ax1, bx1);
    float lty = fmaxf(ay1, by1);
    float rbx = fminf(ax2, bx2);
    float rby = fminf(ay2, by2);
    float w = rbx - ltx; if (w < 0.0f) w = 0.0f;
    float h = rby - lty; if (h < 0.0f) h = 0.0f;
    float inter = w * h;
    return inter / (area_a + area_b - inter);
}

// ---------------- Fused kernel ----------------
__global__ void __launch_bounds__(256) fused_kernel(
        const float* __restrict__ bboxes,
        const float* __restrict__ priors,
        unsigned long long* __restrict__ part1,   // [nchunks][MPAD]
        unsigned long long* __restrict__ partG,   // [N_GT] (atomicMax)
        int* __restrict__ force_n,                // [M] init -1 (chunk 0)
        int M, int gt_chunk) {
#pragma clang fp contract(off)
    int tid = threadIdx.x;
    int lane = tid & 63;
    int wid = tid >> 6;
    int n0 = blockIdx.y * gt_chunk;
    int base_m = blockIdx.x * PRIORS_PER_BLOCK + wid * 256;  // + k*64 + lane

    // Load 4 priors into registers (degenerate zero box for m >= M: iou == 0).
    float px1[4], py1[4], px2[4], py2[4], parea[4];
#pragma unroll
    for (int k = 0; k < 4; ++k) {
        int m = base_m + k * 64 + lane;
        float4 p = (m < M) ? reinterpret_cast<const float4*>(priors)[m]
                           : make_float4(0.f, 0.f, 0.f, 0.f);
        px1[k] = p.x - p.z / 2.0f;
        py1[k] = p.y - p.w / 2.0f;
        px2[k] = p.x + p.z / 2.0f;
        py2[k] = p.y + p.w / 2.0f;
        parea[k] = (px2[k] - px1[k]) * (py2[k] - py1[k]);
    }

    float best[4] = {-1.f, -1.f, -1.f, -1.f};
    int bestj[4] = {0, 0, 0, 0};

    for (int j = 0; j < gt_chunk; ++j) {
        // GT box: index uniform across the wave -> scalar-pipe load (K$).
        float4 g = reinterpret_cast<const float4*>(bboxes)[n0 + j];
        float ga = (g.z - g.x) * (g.w - g.y);

        float iou[4];
#pragma unroll
        for (int k = 0; k < 4; ++k) {
            iou[k] = iou_ab(g.x, g.y, g.z, g.w, ga,
                            px1[k], py1[k], px2[k], py2[k], parea[k]);
            // (a) per-prior argmax: strict > with ascending j == first-max
            if (iou[k] > best[k]) { best[k] = iou[k]; bestj[k] = j; }
        }

        // (b) per-GT max over this wave's 256 priors
        float wmax = fmaxf(fmaxf(iou[0], iou[1]), fmaxf(iou[2], iou[3]));
        wmax = fmaxf(wmax, __shfl_xor(wmax, 1));
        wmax = fmaxf(wmax, __shfl_xor(wmax, 2));
        wmax = fmaxf(wmax, __shfl_xor(wmax, 4));
        wmax = fmaxf(wmax, __shfl_xor(wmax, 8));
        wmax = fmaxf(wmax, __shfl_xor(wmax, 16));
        wmax = fmaxf(wmax, __shfl_xor(wmax, 32));

        unsigned long long b0 = __ballot(iou[0] == wmax);
        unsigned long long b1 = __ballot(iou[1] == wmax);
        unsigned long long b2 = __ballot(iou[2] == wmax);
        unsigned long long b3 = __ballot(iou[3] == wmax);

        // smallest k with a winner, then lowest lane == smallest m
        int wk, wl;
        if (b0)      { wk = 0; wl = __ffsll(b0) - 1; }
        else if (b1) { wk = 1; wl = __ffsll(b1) - 1; }
        else if (b2) { wk = 2; wl = __ffsll(b2) - 1; }
        else         { wk = 3; wl = __ffsll(b3) - 1; }

        if (lane == 0) {
            unsigned wm = (unsigned)(base_m + wk * 64 + wl);
            unsigned long long packed =
                ((unsigned long long)__float_as_uint(wmax) << 32) |
                (unsigned long long)(0xFFFFFFFFu - wm);
            atomicMax(&partG[n0 + j], packed);  // commutative -> deterministic
        }
    }

    size_t row = (size_t)blockIdx.y * MPAD;
#pragma unroll
    for (int k = 0; k < 4; ++k) {
        int m = base_m + k * 64 + lane;
        if (m < M) {
            unsigned n_global = (unsigned)(n0 + bestj[k]);
            part1[row + m] =
                ((unsigned long long)__float_as_uint(best[k]) << 32) |
                (unsigned long long)(0xFFFFFFFFu - n_global);
            if (blockIdx.y == 0) force_n[m] = -1;  // replay-safe init for RS
        }
    }
}

// ---------------- RS: per-GT winner -> forced-assignment scatter -------------
__global__ void rs_kernel(const unsigned long long* __restrict__ partG,
                          int* __restrict__ force_n) {
    int n = blockIdx.x * blockDim.x + threadIdx.x;
    if (n >= N_GT) return;
    unsigned long long v = partG[n];
    int m = (int)(0xFFFFFFFFu - (unsigned)(v & 0xFFFFFFFFull));
    atomicMax(&force_n[m], n);   // duplicate priors: last write in np == max n
}

// ---------------- E: reduce per-prior partials + encode ----------------------
__global__ void __launch_bounds__(256) encode_kernel(
        const float* __restrict__ bboxes,
        const int* __restrict__ labels,
        const float* __restrict__ priors,
        const unsigned long long* __restrict__ part1,  // [nchunks][MPAD]
        const int* __restrict__ force_n,
        float* __restrict__ out, int M, int nchunks) {
#pragma clang fp contract(off)
    int m = blockIdx.x * 256 + threadIdx.x;
    if (m >= M) return;

    unsigned long long best = part1[m];
    for (int c = 1; c < nchunks; ++c) {
        unsigned long long v = part1[(size_t)c * MPAD + m];
        if (v > best) best = v;
    }
    float iou = __uint_as_float((unsigned)(best >> 32));
    int mid = (int)(0xFFFFFFFFu - (unsigned)(best & 0xFFFFFFFFull));

    int f = force_n[m];
    if (f >= 0) { mid = f; iou = POS_THRESH; }

    float4 g = reinterpret_cast<const float4*>(bboxes)[mid];
    float mcx = (g.x + g.z) / 2.0f;
    float mcy = (g.y + g.w) / 2.0f;
    float mw = g.z - g.x;
    float mh = g.w - g.y;

    float4 p = reinterpret_cast<const float4*>(priors)[m];
    float dcx = ((mcx - p.x) / p.z) / 0.1f;
    float dcy = ((mcy - p.y) / p.w) / 0.1f;
    float dw = logf(mw / p.z) / 0.2f;
    float dh = logf(mh / p.w) / 0.2f;

    reinterpret_cast<float4*>(out)[m] = make_float4(dcx, dcy, dw, dh);

    int cls = labels[mid];
    if (iou < POS_THRESH) cls = -1;
    if (iou < NEG_THRESH) cls = 0;
    out[(size_t)4 * M + m] = (float)cls;
}

extern "C" void kernel_launch(void* const* d_in, const int* in_sizes, int n_in,
                              void* d_out, int out_size, void* d_ws, size_t ws_size,
                              hipStream_t stream) {
    const float* bboxes = (const float*)d_in[0];
    const int* labels = (const int*)d_in[1];
    const float* priors = (const float*)d_in[2];
    int M = in_sizes[2] / 4;
    float* out = (float*)d_out;

    // Pick GT-chunk count by workspace budget (part1 is nchunks*MPAD u64).
    auto need = [&](int nc) {
        return (size_t)nc * MPAD * 8 + (size_t)N_GT * 8 + (size_t)MPAD * 4;
    };
    int nchunks = 32;
    if (ws_size < need(32)) nchunks = 16;
    if (ws_size < need(16)) nchunks = 8;
    int gt_chunk = N_GT / nchunks;

    char* ws = (char*)d_ws;
    unsigned long long* part1 = (unsigned long long*)ws;
    unsigned long long* partG = (unsigned long long*)(ws + (size_t)nchunks * MPAD * 8);
    int* force_n = (int*)(ws + (size_t)nchunks * MPAD * 8 + (size_t)N_GT * 8);

    // partG must be 0 before fused_kernel's atomicMax (replay-safe)
    hipMemsetAsync(partG, 0, (size_t)N_GT * 8, stream);

    int mb = (M + PRIORS_PER_BLOCK - 1) / PRIORS_PER_BLOCK;  // 48
    fused_kernel<<<dim3(mb, nchunks), 256, 0, stream>>>(bboxes, priors, part1,
                                                        partG, force_n, M, gt_chunk);
    rs_kernel<<<(N_GT + 255) / 256, 256, 0, stream>>>(partG, force_n);
    encode_kernel<<<(M + 255) / 256, 256, 0, stream>>>(bboxes, labels, priors,
                                                       part1, force_n, out, M, nchunks);
}

// Round 5
// 72.958 us; speedup vs baseline: 1.3569x; 1.3569x over previous
//
#include <hip/hip_runtime.h>

// RetinaNet target encoder for MI355X — round 5: fused one-pass IoU with
// LDS tile decoupling the two argmax reductions (no per-j cross-lane ops).
// Inputs: bboxes [N,4] f32 xyxy, labels [N] i32, priors [M,4] f32 cxcywh.
// Outputs (concat): reg_targets [M,4] f32, cls_targets [M] (written as f32).
//
// N = 1024, M = 49104.
// fused<<<(192, 32)>>>: block = 256 priors x 32-GT chunk.
//   phase 1: thread=prior, j-loop: IoU once -> (a) per-prior argmax in regs
//            (strict > ascending j == numpy first-max), raw iou -> LDS tile.
//            No cross-lane ops, no atomics.
//   phase 2: 8 lanes per GT scan the tile transposed (ascending m, strict >),
//            3-step shfl merge with explicit (iou, m<) tie-break, winner
//            (always >= 0) packed (iou_bits<<32)|(~m) -> partD[block][gt].
// rs: per GT reduce 192 block winners (u64 max == max iou, smallest m) then
//     force_n[m] = atomicMax(n)  (duplicate priors: numpy last-write == max n).
// encode: reduce 32 per-prior partials (strict > ascending chunk == smallest
//     n on ties) + forced overrides + box encode.

static constexpr float NEG_THRESH = 0.4f;
static constexpr float POS_THRESH = 0.5f;
static constexpr int N_GT = 1024;
static constexpr int GT_CHUNK = 32;
static constexpr int NCHUNK = N_GT / GT_CHUNK;   // 32
static constexpr int MPAD = 49152;               // M rounded up to 256
static constexpr int BLK = 256;                  // priors per block
static constexpr int NB = MPAD / BLK;            // 192 prior blocks
static constexpr int STRIDE = 264;               // 264 % 32 == 8 -> <=2-way banks

__device__ __forceinline__ float iou_ab(float ax1, float ay1, float ax2, float ay2,
                                        float area_a,
                                        float bx1, float by1, float bx2, float by2,
                                        float area_b) {
#pragma clang fp contract(off)
    float ltx = fmaxf(ax1, bx1);
    float lty = fmaxf(ay1, by1);
    float rbx = fminf(ax2, bx2);
    float rby = fminf(ay2, by2);
    float w = rbx - ltx; if (w < 0.0f) w = 0.0f;
    float h = rby - lty; if (h < 0.0f) h = 0.0f;
    float inter = w * h;
    return inter / (area_a + area_b - inter);
}

// ---------------- Fused kernel ----------------
__global__ void __launch_bounds__(256) fused_kernel(
        const float* __restrict__ bboxes,
        const float* __restrict__ priors,
        float* __restrict__ part1iou,             // [NCHUNK][MPAD]
        unsigned short* __restrict__ part1idx,    // [NCHUNK][MPAD]
        unsigned long long* __restrict__ partD,   // [NB][N_GT]
        int* __restrict__ force_n,                // [M], init -1 (chunk 0)
        int M) {
#pragma clang fp contract(off)
    __shared__ float tile[GT_CHUNK][STRIDE];

    int tid = threadIdx.x;
    int bx = blockIdx.x;
    int n0 = blockIdx.y * GT_CHUNK;
    int m = bx * BLK + tid;
    bool valid = (m < M);

    // Prior box in registers (zero box for tail: iou computes to 0, masked -1).
    float4 p = valid ? reinterpret_cast<const float4*>(priors)[m]
                     : make_float4(0.f, 0.f, 0.f, 0.f);
    float bx1 = p.x - p.z / 2.0f;
    float by1 = p.y - p.w / 2.0f;
    float bx2 = p.x + p.z / 2.0f;
    float by2 = p.y + p.w / 2.0f;
    float area_b = (bx2 - bx1) * (by2 - by1);

    float best = -1.0f;
    int bestj = 0;

#pragma unroll 4
    for (int j = 0; j < GT_CHUNK; ++j) {
        // GT box: uniform index -> scalar-pipe load (K$ cached).
        float4 g = reinterpret_cast<const float4*>(bboxes)[n0 + j];
        float ga = (g.z - g.x) * (g.w - g.y);
        float iou = iou_ab(g.x, g.y, g.z, g.w, ga, bx1, by1, bx2, by2, area_b);

        // (a) per-prior argmax: strict > ascending j == numpy first-max.
        if (iou > best) { best = iou; bestj = j; }

        tile[j][tid] = valid ? iou : -1.0f;   // invalid lanes never win (>= 0 real)
    }

    if (valid) {
        size_t row = (size_t)blockIdx.y * MPAD + m;
        part1iou[row] = best;
        part1idx[row] = (unsigned short)(n0 + bestj);
        if (blockIdx.y == 0) force_n[m] = -1;   // replay-safe init for rs
    }

    __syncthreads();

    // phase 2: per-GT argmax over this block's 256 priors.
    int j = tid >> 3;          // 0..31  (8 lanes per GT, same wave)
    int sub = tid & 7;
    int m0 = bx * BLK;

    float bi = -2.0f;
    int bm = 0;
#pragma unroll 8
    for (int k = 0; k < BLK / 8; ++k) {
        int i = sub + 8 * k;                    // ascending i == ascending m
        float v = tile[j][i];
        if (v > bi) { bi = v; bm = m0 + i; }    // strict > == smallest m on tie
    }
#pragma unroll
    for (int mask = 1; mask < 8; mask <<= 1) {  // lanes share j (tid>>3 const)
        float oi = __shfl_xor(bi, mask);
        int om = __shfl_xor(bm, mask);
        if (oi > bi || (oi == bi && om < bm)) { bi = oi; bm = om; }
    }
    if (sub == 0) {
        // winner iou >= 0 always (every block has >=208 valid priors)
        partD[(size_t)bx * N_GT + n0 + j] =
            ((unsigned long long)__float_as_uint(bi) << 32) |
            (unsigned long long)(0xFFFFFFFFu - (unsigned)bm);
    }
}

// ---------------- RS: per-GT winner -> forced-assignment scatter -------------
__global__ void rs_kernel(const unsigned long long* __restrict__ partD,
                          int* __restrict__ force_n) {
    int n = blockIdx.x * blockDim.x + threadIdx.x;
    if (n >= N_GT) return;
    unsigned long long best = 0ULL;
    for (int c = 0; c < NB; ++c) {              // coalesced: lanes read adjacent n
        unsigned long long v = partD[(size_t)c * N_GT + n];
        if (v > best) best = v;
    }
    int m = (int)(0xFFFFFFFFu - (unsigned)(best & 0xFFFFFFFFull));
    atomicMax(&force_n[m], n);   // duplicate priors: last write in np == max n
}

// ---------------- E: reduce per-prior partials + encode ----------------------
__global__ void __launch_bounds__(256) encode_kernel(
        const float* __restrict__ bboxes,
        const int* __restrict__ labels,
        const float* __restrict__ priors,
        const float* __restrict__ part1iou,
        const unsigned short* __restrict__ part1idx,
        const int* __restrict__ force_n,
        float* __restrict__ out, int M) {
#pragma clang fp contract(off)
    int m = blockIdx.x * 256 + threadIdx.x;
    if (m >= M) return;

    float bi = part1iou[m];
    int bn = part1idx[m];
    for (int c = 1; c < NCHUNK; ++c) {
        float v = part1iou[(size_t)c * MPAD + m];
        if (v > bi) { bi = v; bn = part1idx[(size_t)c * MPAD + m]; }
    }   // strict > ascending c == smallest n on ties (numpy first-max)

    float iou = bi;
    int mid = bn;
    int f = force_n[m];
    if (f >= 0) { mid = f; iou = POS_THRESH; }

    float4 g = reinterpret_cast<const float4*>(bboxes)[mid];
    float mcx = (g.x + g.z) / 2.0f;
    float mcy = (g.y + g.w) / 2.0f;
    float mw = g.z - g.x;
    float mh = g.w - g.y;

    float4 p = reinterpret_cast<const float4*>(priors)[m];
    float dcx = ((mcx - p.x) / p.z) / 0.1f;
    float dcy = ((mcy - p.y) / p.w) / 0.1f;
    float dw = logf(mw / p.z) / 0.2f;
    float dh = logf(mh / p.w) / 0.2f;

    reinterpret_cast<float4*>(out)[m] = make_float4(dcx, dcy, dw, dh);

    int cls = labels[mid];
    if (iou < POS_THRESH) cls = -1;
    if (iou < NEG_THRESH) cls = 0;
    out[(size_t)4 * M + m] = (float)cls;
}

extern "C" void kernel_launch(void* const* d_in, const int* in_sizes, int n_in,
                              void* d_out, int out_size, void* d_ws, size_t ws_size,
                              hipStream_t stream) {
    const float* bboxes = (const float*)d_in[0];
    const int* labels = (const int*)d_in[1];
    const float* priors = (const float*)d_in[2];
    int M = in_sizes[2] / 4;
    float* out = (float*)d_out;

    // Workspace layout (~9.6 MB total):
    char* ws = (char*)d_ws;
    float* part1iou = (float*)ws;                                        // 6.29 MB
    unsigned short* part1idx = (unsigned short*)(ws + (size_t)NCHUNK * MPAD * 4);  // 3.15 MB @ +6.29
    unsigned long long* partD = (unsigned long long*)(ws + (size_t)NCHUNK * MPAD * 6);  // 1.57 MB
    int* force_n = (int*)(ws + (size_t)NCHUNK * MPAD * 6 + (size_t)NB * N_GT * 8);

    fused_kernel<<<dim3(NB, NCHUNK), 256, 0, stream>>>(bboxes, priors, part1iou,
                                                       part1idx, partD, force_n, M);
    rs_kernel<<<(N_GT + 255) / 256, 256, 0, stream>>>(partD, force_n);
    encode_kernel<<<(MPAD + 255) / 256, 256, 0, stream>>>(bboxes, labels, priors,
                                                          part1iou, part1idx,
                                                          force_n, out, M);
}